// Round 6
// baseline (17.703 us; speedup 1.0000x reference)
//
#include <hip/hip_runtime.h>

// QuantumKernelAttention, rank-16 factorization + MFMA epilogue (R9):
//   K[b,i,j] = prod_k ( c_ik c_jk + s_ik s_jk ) = sum_t F[i,t] F[j,t]  (rank 16)
//   Gram tile via v_mfma_f32_32x32x16_f16; E = exp(|K|) via packed-f16 deg-4
//   Horner (no trans pipe); E fed to a second MFMA vs [x | 1]^T for sum(e*x)
//   and sum(e) (softmax denominator).
// R9 vs R8: TWO-KERNEL SPLIT. R5/R7/R8 (three different main loops) all sit
// at 12.0-12.1us while issue/critical-path models say ~2-3us -> main loop is
// exonerated; the never-varied phase is the 16x-redundant sincos staging.
// Kernel 1 (64 blocks) computes F + XT once per batch into d_ws (~1.4MB,
// L2-resident). Kernel 2 = R8 with staging replaced by 4 global_load_lds
// dwordx4 (XOR-swizzle folded into the per-lane GLOBAL source address, LDS
// dest linear - m173 pattern; swizzle is an involution) + a 645-slot XT copy.
// Per-block staging drops ~1500 -> ~400 cycles and all redundant trans work
// disappears. If dur stays ~12us, a fixed launch floor is confirmed.

typedef _Float16 f16x8 __attribute__((ext_vector_type(8)));
typedef _Float16 h2    __attribute__((ext_vector_type(2)));
typedef float    f32x16 __attribute__((ext_vector_type(16)));
typedef unsigned int u32x4 __attribute__((ext_vector_type(4)));

#define SQ 1024
#define NTHREADS 512   // 8 waves: 2 row-tiles x 4 j-quarters
#define ROWS 64        // output rows per block
#define XT_SLOTS 645   // 5 rows * 129 f16x8 (pitch 1032 f16)
#define XT_PITCH 1032

// workspace layout (bytes); ws is >=256MB, zero-filled by harness each iter
#define F0_OFF 0                        // 32 * 1024 * 16B = 512 KB
#define F1_OFF (32 * 1024 * 16)         // 512 KB
#define XT_OFF (2 * 32 * 1024 * 16)     // XT: 32 batches x 704 slots x 16B
#define XT_BATCH_BYTES (704 * 16)

#if __has_builtin(__builtin_amdgcn_permlane32_swap)
__device__ __forceinline__ void pl32swap(unsigned &a, unsigned &b) {
    auto r = __builtin_amdgcn_permlane32_swap(a, b, false, false);
    a = r[0]; b = r[1];
}
#else
__device__ __forceinline__ void pl32swap(unsigned &a, unsigned &b) {
    asm("v_permlane32_swap_b32 %0, %1" : "+v"(a), "+v"(b));
}
#endif

// e^|.| for a pair of f32, evaluated in packed f16 (no trans pipe).
// Deg-4 Chebyshev-derived Horner on [0,1]: max poly err ~3e-5 on e^t.
__device__ __forceinline__ unsigned pexp_abs(float a, float b) {
    auto tp = __builtin_amdgcn_cvt_pkrtz(fabsf(a), fabsf(b)); // abs -> src mods
    h2 t = __builtin_bit_cast(h2, tp);
    const h2 C4 = {(_Float16)0.0695580f, (_Float16)0.0695580f};
    const h2 C3 = {(_Float16)0.1399810f, (_Float16)0.1399810f};
    const h2 C2 = {(_Float16)0.5100530f, (_Float16)0.5100530f};
    const h2 C1 = {(_Float16)0.9986730f, (_Float16)0.9986730f};
    const h2 C0 = {(_Float16)0.9999940f, (_Float16)0.9999940f};
    h2 p = __builtin_elementwise_fma(C4, t, C3);
    p = __builtin_elementwise_fma(p, t, C2);
    p = __builtin_elementwise_fma(p, t, C1);
    p = __builtin_elementwise_fma(p, t, C0);
    return __builtin_bit_cast(unsigned, p);
}

// ---- kernel 1: compute F (f16, unswizzled) + XT (f16) once per batch ----
__global__ __launch_bounds__(512)
void qka_stage(const float* __restrict__ x, char* __restrict__ ws) {
    const int bid = blockIdx.x;          // 64 blocks: 2 per batch
    const int b   = bid >> 1;
    const int j   = ((bid & 1) << 9) + threadIdx.x;
    float4 v = ((const float4*)(x + (size_t)b * SQ * 4))[j];
    float c0 = __cosf(0.5f * v.x), s0 = __sinf(0.5f * v.x);
    float c1 = __cosf(0.5f * v.y), s1 = __sinf(0.5f * v.y);
    float c2 = __cosf(0.5f * v.z), s2 = __sinf(0.5f * v.z);
    float c3 = __cosf(0.5f * v.w), s3 = __sinf(0.5f * v.w);
    float m0 = c0 * c1, m1 = s0 * c1, m2 = c0 * s1, m3 = s0 * s1;
    float n0 = m0 * c2, n1 = m1 * c2, n2 = m2 * c2, n3 = m3 * c2;
    float n4 = m0 * s2, n5 = m1 * s2, n6 = m2 * s2, n7 = m3 * s2;
    f16x8 p0, p1;
    p0[0] = (_Float16)(n0 * c3); p0[1] = (_Float16)(n1 * c3);
    p0[2] = (_Float16)(n2 * c3); p0[3] = (_Float16)(n3 * c3);
    p0[4] = (_Float16)(n4 * c3); p0[5] = (_Float16)(n5 * c3);
    p0[6] = (_Float16)(n6 * c3); p0[7] = (_Float16)(n7 * c3);
    p1[0] = (_Float16)(n0 * s3); p1[1] = (_Float16)(n1 * s3);
    p1[2] = (_Float16)(n2 * s3); p1[3] = (_Float16)(n3 * s3);
    p1[4] = (_Float16)(n4 * s3); p1[5] = (_Float16)(n5 * s3);
    p1[6] = (_Float16)(n6 * s3); p1[7] = (_Float16)(n7 * s3);
    ((f16x8*)(ws + F0_OFF))[b * SQ + j] = p0;
    ((f16x8*)(ws + F1_OFF))[b * SQ + j] = p1;
    _Float16* xt = (_Float16*)(ws + XT_OFF + (size_t)b * XT_BATCH_BYTES);
    xt[0 * XT_PITCH + j] = (_Float16)v.x;
    xt[1 * XT_PITCH + j] = (_Float16)v.y;
    xt[2 * XT_PITCH + j] = (_Float16)v.z;
    xt[3 * XT_PITCH + j] = (_Float16)v.w;
    xt[4 * XT_PITCH + j] = (_Float16)1.0f;
}

// ---- kernel 2: attention (staging = direct-to-LDS copies) ----
__global__ __launch_bounds__(NTHREADS, 4)
void qka_kernel(const char* __restrict__ ws, float* __restrict__ out) {
    __shared__ f16x8 lds_F0[SQ];          // 16 KB  F[j][k=0..7], rows swizzled
    __shared__ f16x8 lds_F1[SQ];          // 16 KB  F[j][k=8..15]
    __shared__ f16x8 lds_XT[XT_SLOTS];    // ~10.1 KB

    const int bid   = blockIdx.x;
    const int b     = bid >> 4;          // 16 row-tiles (of 64) per batch
    const int Ibase = (bid & 15) * ROWS;
    const int tid   = threadIdx.x;

    const f16x8* F0g = (const f16x8*)(ws + F0_OFF) + (size_t)b * SQ;
    const f16x8* F1g = (const f16x8*)(ws + F1_OFF) + (size_t)b * SQ;
    const f16x8* XTg = (const f16x8*)(ws + XT_OFF + (size_t)b * XT_BATCH_BYTES);

    // F halves: global_load_lds dwordx4, LDS dest linear, source address
    // carries the XOR swizzle (involution): lds_F[l] = F[l ^ ((l>>3)&7)].
    {
        const int w    = tid >> 6;
        const int ln64 = tid & 63;
        #pragma unroll
        for (int i = 0; i < 2; ++i) {
            int base = w * 128 + i * 64;         // wave-uniform LDS slot base
            int l    = base + ln64;
            int s    = l ^ ((l >> 3) & 7);       // per-lane swizzled source
            __builtin_amdgcn_global_load_lds(
                (const __attribute__((address_space(1))) unsigned int*)&F0g[s],
                (__attribute__((address_space(3))) unsigned int*)&lds_F0[base],
                16, 0, 0);
            __builtin_amdgcn_global_load_lds(
                (const __attribute__((address_space(1))) unsigned int*)&F1g[s],
                (__attribute__((address_space(3))) unsigned int*)&lds_F1[base],
                16, 0, 0);
        }
    }
    // XT: plain 16B copy of 645 slots (layout identical to ws)
    for (int t = tid; t < XT_SLOTS; t += NTHREADS)
        lds_XT[t] = XTg[t];
    __syncthreads();

    // ---- main: wave = (row-tile rt, j-quarter q); 8 tiles of 32 j each ----
    const int wid  = tid >> 6;
    const int q    = wid & 3;            // j-quarter: j in [256q, 256q+256)
    const int rt   = wid >> 2;           // row-tile within block (0/1)
    const int lane = tid & 63;
    const int h    = lane >> 5;          // k-half selector
    const int ln   = lane & 31;

    const f16x8* Fh = h ? lds_F1 : lds_F0;
    int ib = Ibase + rt * 32 + ln; ib ^= (ib >> 3) & 7;
    const f16x8 bfrag = Fh[ib];          // B: F[I-tile] rows (col n = i)

    // PV B-frag: lane col n reads X^T row min(n,4); cols >=5 never read back.
    const int rowsel = (ln < 4) ? ln : 4;
    const int xbase  = rowsel * 129 + q * 32 + h;   // f16x8 index

    f32x16 oacc0 = (f32x16)(0.0f);       // e-rows k=j' 0..15
    f32x16 oacc1 = (f32x16)(0.0f);       // e-rows k=j' 16..31

    // Gram for tile 0, pipelined one tile ahead of the poly/PV stage.
    int ja0 = q * 256 + ln;
    f16x8 af0 = Fh[ja0 ^ ((ja0 >> 3) & 7)];
    f32x16 d = __builtin_amdgcn_mfma_f32_32x32x16_f16(
        af0, bfrag, (f32x16)(0.0f), 0, 0, 0);

    #pragma unroll 2
    for (int t = 0; t < 8; ++t) {
        // Issue this iteration's LDS reads first (latency hidden under poly).
        f16x8 afn;
        if (t < 7) {
            int jn = q * 256 + (t + 1) * 32 + ln;
            afn = Fh[jn ^ ((jn >> 3) & 7)];
        }
        f16x8 xf0 = lds_XT[xbase + t * 4];        // X rows [jb, jb+16)
        f16x8 xf1 = lds_XT[xbase + t * 4 + 2];    // X rows [jb+16, jb+32)
        // d[r] = K[j', i], j' = (r&3)+8(r>>2)+4h; e = poly(|d|) in packed f16.
        unsigned q0 = pexp_abs(d[0],  d[1]);
        unsigned q1 = pexp_abs(d[2],  d[3]);
        unsigned q2 = pexp_abs(d[4],  d[5]);
        unsigned q3 = pexp_abs(d[6],  d[7]);
        unsigned q4 = pexp_abs(d[8],  d[9]);
        unsigned q5 = pexp_abs(d[10], d[11]);
        unsigned q6 = pexp_abs(d[12], d[13]);
        unsigned q7 = pexp_abs(d[14], d[15]);
        // Gram for tile t+1; d is dead (consumed above), dn reuses its regs.
        f32x16 dn;
        if (t < 7)
            dn = __builtin_amdgcn_mfma_f32_32x32x16_f16(
                afn, bfrag, (f32x16)(0.0f), 0, 0, 0);
        pl32swap(q0, q2); pl32swap(q1, q3);   // frag0 dwords 0..3 (k = 0..15)
        pl32swap(q4, q6); pl32swap(q5, q7);   // frag1 dwords 0..3 (k = 16..31)
        u32x4 w0 = {q0, q1, q2, q3};
        u32x4 w1 = {q4, q5, q6, q7};
        f16x8 ef0 = __builtin_bit_cast(f16x8, w0);
        f16x8 ef1 = __builtin_bit_cast(f16x8, w1);
        oacc0 = __builtin_amdgcn_mfma_f32_32x32x16_f16(ef0, xf0, oacc0, 0, 0, 0);
        oacc1 = __builtin_amdgcn_mfma_f32_32x32x16_f16(ef1, xf1, oacc1, 0, 0, 0);
        if (t < 7) d = dn;
    }

    // ---- cross-wave combine: partials in LDS (alias onto lds_F0, now dead) ----
    __syncthreads();                     // all waves done reading F / XT
    float* ps = (float*)lds_F0;          // [q=4][64 rows][8 cols f32] = 8 KB
    if (ln < 5) {                        // cols 0..4 valid, both halves
        #pragma unroll
        for (int r = 0; r < 16; ++r) {
            int m = (r & 3) + 8 * (r >> 2) + 4 * h;   // row within 32-tile
            ps[(q * 64 + rt * 32 + m) * 8 + ln] = oacc0[r] + oacc1[r];
        }
    }
    __syncthreads();

    if (tid < ROWS) {
        float nx = 0.f, ny = 0.f, nz = 0.f, nw = 0.f, den = 0.f;
        #pragma unroll
        for (int qq = 0; qq < 4; ++qq) {
            const float* p = &ps[(qq * 64 + tid) * 8];
            nx += p[0]; ny += p[1]; nz += p[2]; nw += p[3]; den += p[4];
        }
        float inv = 1.0f / den;
        ((float4*)out)[(size_t)b * SQ + Ibase + tid] =
            make_float4(nx * inv, ny * inv, nz * inv, nw * inv);
    }
}

extern "C" void kernel_launch(void* const* d_in, const int* in_sizes, int n_in,
                              void* d_out, int out_size, void* d_ws, size_t ws_size,
                              hipStream_t stream) {
    const float* x = (const float*)d_in[0];
    float* out = (float*)d_out;
    char* ws = (char*)d_ws;
    qka_stage<<<dim3(64), dim3(512), 0, stream>>>(x, ws);
    qka_kernel<<<dim3(32 * (SQ / ROWS)), dim3(NTHREADS), 0, stream>>>(ws, out);
}

// Round 7
// 14.050 us; speedup vs baseline: 1.2600x; 1.2600x over previous
//
#include <hip/hip_runtime.h>

// QuantumKernelAttention, rank-16 factorization + MFMA epilogue (R10):
//   K[b,i,j] = prod_k ( c_ik c_jk + s_ik s_jk ) = sum_t F[i,t] F[j,t]  (rank 16)
//   Gram tile via v_mfma_f32_32x32x16_f16; E = exp(|K|) via packed-f16 deg-4
//   Horner (no trans pipe); E fed to a second MFMA vs [x | 1]^T for sum(e*x)
//   and sum(e).
// R10 vs R8: WAVE-AUTONOMOUS blocks, zero barriers before the epilogue.
//   R9 calibrated per-dispatch overhead at ~4-5us (split cost +5.6us); model
//   says execution ~6-7us of the 12, and the only never-varied in-kernel
//   phase is the cooperative staging + block-wide __syncthreads convoy.
//   Now: 256-thread blocks (4 waves), ROWS=32, 1024 blocks. Each wave stages
//   ONLY its own j-quarter (4 rows/lane -> LDS it alone reads: wave-local
//   RAW, no barrier, compiler's lgkmcnt suffices) and computes its B-fragment
//   (I-tile rows) entirely in-register (w3 = h ? s3 : c3 cndmask). First
//   __syncthreads in the kernel is the epilogue partial-combine.

typedef _Float16 f16x8 __attribute__((ext_vector_type(8)));
typedef _Float16 h2    __attribute__((ext_vector_type(2)));
typedef float    f32x16 __attribute__((ext_vector_type(16)));
typedef unsigned int u32x4 __attribute__((ext_vector_type(4)));

#define SQ 1024
#define NTHREADS 256   // 4 waves; wave q owns j-quarter [256q, 256q+256)
#define ROWS 32        // output rows per block

#if __has_builtin(__builtin_amdgcn_permlane32_swap)
__device__ __forceinline__ void pl32swap(unsigned &a, unsigned &b) {
    auto r = __builtin_amdgcn_permlane32_swap(a, b, false, false);
    a = r[0]; b = r[1];
}
#else
__device__ __forceinline__ void pl32swap(unsigned &a, unsigned &b) {
    asm("v_permlane32_swap_b32 %0, %1" : "+v"(a), "+v"(b));
}
#endif

// e^|.| for a pair of f32, evaluated in packed f16 (no trans pipe).
// Deg-4 Chebyshev-derived Horner on [0,1]: max poly err ~3e-5 on e^t.
__device__ __forceinline__ unsigned pexp_abs(float a, float b) {
    auto tp = __builtin_amdgcn_cvt_pkrtz(fabsf(a), fabsf(b)); // abs -> src mods
    h2 t = __builtin_bit_cast(h2, tp);
    const h2 C4 = {(_Float16)0.0695580f, (_Float16)0.0695580f};
    const h2 C3 = {(_Float16)0.1399810f, (_Float16)0.1399810f};
    const h2 C2 = {(_Float16)0.5100530f, (_Float16)0.5100530f};
    const h2 C1 = {(_Float16)0.9986730f, (_Float16)0.9986730f};
    const h2 C0 = {(_Float16)0.9999940f, (_Float16)0.9999940f};
    h2 p = __builtin_elementwise_fma(C4, t, C3);
    p = __builtin_elementwise_fma(p, t, C2);
    p = __builtin_elementwise_fma(p, t, C1);
    p = __builtin_elementwise_fma(p, t, C0);
    return __builtin_bit_cast(unsigned, p);
}

// sincos(x/2) x4 + rank-16 tensor product halves (n*c3 -> p0, n*s3 -> p1)
__device__ __forceinline__ void fhalves(float4 v, f16x8 &p0, f16x8 &p1) {
    float c0 = __cosf(0.5f * v.x), s0 = __sinf(0.5f * v.x);
    float c1 = __cosf(0.5f * v.y), s1 = __sinf(0.5f * v.y);
    float c2 = __cosf(0.5f * v.z), s2 = __sinf(0.5f * v.z);
    float c3 = __cosf(0.5f * v.w), s3 = __sinf(0.5f * v.w);
    float m0 = c0 * c1, m1 = s0 * c1, m2 = c0 * s1, m3 = s0 * s1;
    float n0 = m0 * c2, n1 = m1 * c2, n2 = m2 * c2, n3 = m3 * c2;
    float n4 = m0 * s2, n5 = m1 * s2, n6 = m2 * s2, n7 = m3 * s2;
    p0[0] = (_Float16)(n0 * c3); p0[1] = (_Float16)(n1 * c3);
    p0[2] = (_Float16)(n2 * c3); p0[3] = (_Float16)(n3 * c3);
    p0[4] = (_Float16)(n4 * c3); p0[5] = (_Float16)(n5 * c3);
    p0[6] = (_Float16)(n6 * c3); p0[7] = (_Float16)(n7 * c3);
    p1[0] = (_Float16)(n0 * s3); p1[1] = (_Float16)(n1 * s3);
    p1[2] = (_Float16)(n2 * s3); p1[3] = (_Float16)(n3 * s3);
    p1[4] = (_Float16)(n4 * s3); p1[5] = (_Float16)(n5 * s3);
    p1[6] = (_Float16)(n6 * s3); p1[7] = (_Float16)(n7 * s3);
}

__global__ __launch_bounds__(NTHREADS, 4)
void qka_kernel(const float* __restrict__ x, float* __restrict__ out) {
    // F factors, k-halves split; rows XOR-swizzled (j ^ ((j>>3)&7), stays
    // within each 64-row group) so ds_read_b128 of 32 rows is conflict-minimal.
    __shared__ f16x8 lds_F0[SQ];        // 16 KB  F[j][k=0..7]
    __shared__ f16x8 lds_F1[SQ];        // 16 KB  F[j][k=8..15]
    __shared__ f16x8 lds_XT[5 * 129];   // ~10.1 KB, pitch 129 f16x8

    const int bid   = blockIdx.x;
    const int b     = bid >> 5;          // 32 row-tiles per batch
    const int Ibase = (bid & 31) * ROWS;
    const int tid   = threadIdx.x;

    const int q    = tid >> 6;           // wave id = j-quarter
    const int lane = tid & 63;
    const int h    = lane >> 5;          // k-half selector
    const int ln   = lane & 31;

    const float4* xb  = (const float4*)(x + (size_t)b * SQ * 4);
    _Float16*     xtp = (_Float16*)lds_XT;

    // ---- issue all global loads first (cold-HBM latency overlaps compute) ----
    const int jbase = q * 256;
    float4 vI = xb[Ibase + ln];                  // B-fragment row (in-register)
    float4 v0 = xb[jbase + lane];
    float4 v1 = xb[jbase + lane + 64];
    float4 v2 = xb[jbase + lane + 128];
    float4 v3 = xb[jbase + lane + 192];

    // ---- B-fragment in-register: F_h[Ibase+ln][.] (no LDS, no barrier) ----
    f16x8 bfrag;
    {
        float c0 = __cosf(0.5f * vI.x), s0 = __sinf(0.5f * vI.x);
        float c1 = __cosf(0.5f * vI.y), s1 = __sinf(0.5f * vI.y);
        float c2 = __cosf(0.5f * vI.z), s2 = __sinf(0.5f * vI.z);
        float c3 = __cosf(0.5f * vI.w), s3 = __sinf(0.5f * vI.w);
        float w3 = h ? s3 : c3;                  // cndmask, not divergence
        float m0 = c0 * c1, m1 = s0 * c1, m2 = c0 * s1, m3 = s0 * s1;
        float n0 = m0 * c2, n1 = m1 * c2, n2 = m2 * c2, n3 = m3 * c2;
        float n4 = m0 * s2, n5 = m1 * s2, n6 = m2 * s2, n7 = m3 * s2;
        bfrag[0] = (_Float16)(n0 * w3); bfrag[1] = (_Float16)(n1 * w3);
        bfrag[2] = (_Float16)(n2 * w3); bfrag[3] = (_Float16)(n3 * w3);
        bfrag[4] = (_Float16)(n4 * w3); bfrag[5] = (_Float16)(n5 * w3);
        bfrag[6] = (_Float16)(n6 * w3); bfrag[7] = (_Float16)(n7 * w3);
    }

    // ---- wave-local staging of own quarter: F (swizzled) + XT cols ----
    {
        float4 vv[4] = {v0, v1, v2, v3};
        #pragma unroll
        for (int i = 0; i < 4; ++i) {
            int j = jbase + lane + i * 64;
            f16x8 p0, p1;
            fhalves(vv[i], p0, p1);
            int sj = j ^ ((j >> 3) & 7);
            lds_F0[sj] = p0;
            lds_F1[sj] = p1;
            xtp[0 * 1032 + j] = (_Float16)vv[i].x;
            xtp[1 * 1032 + j] = (_Float16)vv[i].y;
            xtp[2 * 1032 + j] = (_Float16)vv[i].z;
            xtp[3 * 1032 + j] = (_Float16)vv[i].w;
            xtp[4 * 1032 + j] = (_Float16)1.0f;
        }
    }
    // NO __syncthreads: every LDS word this wave reads below was written by
    // this wave above; compiler-inserted lgkmcnt orders the wave-local RAW.

    const f16x8* Fh = h ? lds_F1 : lds_F0;
    // PV B-frag: lane col n reads X^T row min(n,4); cols >=5 never read back.
    const int rowsel = (ln < 4) ? ln : 4;
    const int xbase  = rowsel * 129 + q * 32 + h;   // f16x8 index

    f32x16 oacc0 = (f32x16)(0.0f);       // e-rows k=j' 0..15
    f32x16 oacc1 = (f32x16)(0.0f);       // e-rows k=j' 16..31

    // Gram for tile 0, pipelined one tile ahead of the poly/PV stage.
    int ja0 = jbase + ln;
    f16x8 af0 = Fh[ja0 ^ ((ja0 >> 3) & 7)];
    f32x16 d = __builtin_amdgcn_mfma_f32_32x32x16_f16(
        af0, bfrag, (f32x16)(0.0f), 0, 0, 0);

    #pragma unroll 2
    for (int t = 0; t < 8; ++t) {
        // Issue this iteration's LDS reads first (latency hidden under poly).
        f16x8 afn;
        if (t < 7) {
            int jn = jbase + (t + 1) * 32 + ln;
            afn = Fh[jn ^ ((jn >> 3) & 7)];
        }
        f16x8 xf0 = lds_XT[xbase + t * 4];        // X rows [jb, jb+16)
        f16x8 xf1 = lds_XT[xbase + t * 4 + 2];    // X rows [jb+16, jb+32)
        // d[r] = K[j', i], j' = (r&3)+8(r>>2)+4h; e = poly(|d|) in packed f16.
        unsigned q0 = pexp_abs(d[0],  d[1]);
        unsigned q1 = pexp_abs(d[2],  d[3]);
        unsigned q2 = pexp_abs(d[4],  d[5]);
        unsigned q3 = pexp_abs(d[6],  d[7]);
        unsigned q4 = pexp_abs(d[8],  d[9]);
        unsigned q5 = pexp_abs(d[10], d[11]);
        unsigned q6 = pexp_abs(d[12], d[13]);
        unsigned q7 = pexp_abs(d[14], d[15]);
        // Gram for tile t+1; d is dead (consumed above), dn reuses its regs.
        f32x16 dn;
        if (t < 7)
            dn = __builtin_amdgcn_mfma_f32_32x32x16_f16(
                afn, bfrag, (f32x16)(0.0f), 0, 0, 0);
        pl32swap(q0, q2); pl32swap(q1, q3);   // frag0 dwords 0..3 (k = 0..15)
        pl32swap(q4, q6); pl32swap(q5, q7);   // frag1 dwords 0..3 (k = 16..31)
        u32x4 w0 = {q0, q1, q2, q3};
        u32x4 w1 = {q4, q5, q6, q7};
        f16x8 ef0 = __builtin_bit_cast(f16x8, w0);
        f16x8 ef1 = __builtin_bit_cast(f16x8, w1);
        oacc0 = __builtin_amdgcn_mfma_f32_32x32x16_f16(ef0, xf0, oacc0, 0, 0, 0);
        oacc1 = __builtin_amdgcn_mfma_f32_32x32x16_f16(ef1, xf1, oacc1, 0, 0, 0);
        if (t < 7) d = dn;
    }

    // ---- cross-wave combine: partials in LDS (alias onto lds_F0, now dead) ----
    __syncthreads();                     // first barrier in the kernel
    float* ps = (float*)lds_F0;          // [q=4][32 rows][8 cols f32] = 4 KB
    if (ln < 5) {                        // cols 0..4 valid, both halves
        #pragma unroll
        for (int r = 0; r < 16; ++r) {
            int m = (r & 3) + 8 * (r >> 2) + 4 * h;   // row within 32-tile
            ps[(q * 32 + m) * 8 + ln] = oacc0[r] + oacc1[r];
        }
    }
    __syncthreads();

    if (tid < ROWS) {
        float nx = 0.f, ny = 0.f, nz = 0.f, nw = 0.f, den = 0.f;
        #pragma unroll
        for (int qq = 0; qq < 4; ++qq) {
            const float* p = &ps[(qq * 32 + tid) * 8];
            nx += p[0]; ny += p[1]; nz += p[2]; nw += p[3]; den += p[4];
        }
        float inv = 1.0f / den;
        ((float4*)out)[(size_t)b * SQ + Ibase + tid] =
            make_float4(nx * inv, ny * inv, nz * inv, nw * inv);
    }
}

extern "C" void kernel_launch(void* const* d_in, const int* in_sizes, int n_in,
                              void* d_out, int out_size, void* d_ws, size_t ws_size,
                              hipStream_t stream) {
    const float* x = (const float*)d_in[0];
    float* out = (float*)d_out;
    dim3 grid(32 * (SQ / ROWS));   // 1024 blocks
    dim3 block(NTHREADS);
    qka_kernel<<<grid, block, 0, stream>>>(x, out);
}

// Round 8
// 12.358 us; speedup vs baseline: 1.4326x; 1.1370x over previous
//
#include <hip/hip_runtime.h>

// QuantumKernelAttention, rank-16 factorization + MFMA epilogue (R11):
//   K[b,i,j] = prod_k ( c_ik c_jk + s_ik s_jk ) = sum_t F[i,t] F[j,t]  (rank 16)
//   Gram tile via v_mfma_f32_32x32x16_f16; E = exp(|K|) via packed-f16 deg-4
//   Horner (no trans pipe); E fed to a second MFMA vs [x | 1]^T for sum(e*x)
//   and sum(e) (softmax denominator).
// R11 vs R8: block-count lever, third application. Evidence: R4(1024blk)=13.5,
// R5(512blk)=12.1, R10(1024blk,no-barrier)=14.1 -> per-block staging overhead
// (~1us serial per extra block-slot/CU: cold-load ramp + redundant sincos +
// LDS-port writes) is the live cost; barriers/inner-loop are exonerated
// (R5/R7/R8 identical within noise). Now 256 blocks x 1024 threads (16 waves
// = 4 row-tiles x 4 j-quarters), ROWS=128, grid == CU count. Per-wave main
// loop identical to R8 (32 rows x 256 j); occupancy still 4 waves/SIMD;
// staging redundancy halves (1 point/thread). LDS 42KB; partial array = 16KB
// = exact lds_F0 alias.

typedef _Float16 f16x8 __attribute__((ext_vector_type(8)));
typedef _Float16 h2    __attribute__((ext_vector_type(2)));
typedef float    f32x16 __attribute__((ext_vector_type(16)));
typedef unsigned int u32x4 __attribute__((ext_vector_type(4)));

#define SQ 1024
#define NTHREADS 1024  // 16 waves: 4 row-tiles x 4 j-quarters
#define ROWS 128       // output rows per block

#if __has_builtin(__builtin_amdgcn_permlane32_swap)
__device__ __forceinline__ void pl32swap(unsigned &a, unsigned &b) {
    auto r = __builtin_amdgcn_permlane32_swap(a, b, false, false);
    a = r[0]; b = r[1];
}
#else
__device__ __forceinline__ void pl32swap(unsigned &a, unsigned &b) {
    asm("v_permlane32_swap_b32 %0, %1" : "+v"(a), "+v"(b));
}
#endif

// e^|.| for a pair of f32, evaluated in packed f16 (no trans pipe).
// Deg-4 Chebyshev-derived Horner on [0,1]: max poly err ~3e-5 on e^t.
__device__ __forceinline__ unsigned pexp_abs(float a, float b) {
    auto tp = __builtin_amdgcn_cvt_pkrtz(fabsf(a), fabsf(b)); // abs -> src mods
    h2 t = __builtin_bit_cast(h2, tp);
    const h2 C4 = {(_Float16)0.0695580f, (_Float16)0.0695580f};
    const h2 C3 = {(_Float16)0.1399810f, (_Float16)0.1399810f};
    const h2 C2 = {(_Float16)0.5100530f, (_Float16)0.5100530f};
    const h2 C1 = {(_Float16)0.9986730f, (_Float16)0.9986730f};
    const h2 C0 = {(_Float16)0.9999940f, (_Float16)0.9999940f};
    h2 p = __builtin_elementwise_fma(C4, t, C3);
    p = __builtin_elementwise_fma(p, t, C2);
    p = __builtin_elementwise_fma(p, t, C1);
    p = __builtin_elementwise_fma(p, t, C0);
    return __builtin_bit_cast(unsigned, p);
}

__global__ __launch_bounds__(NTHREADS, 4)
void qka_kernel(const float* __restrict__ x, float* __restrict__ out) {
    // F factors, k-halves split; rows XOR-swizzled (j ^ ((j>>3)&7)) so a wave's
    // ds_read_b128 of 32 consecutive rows is conflict-minimal.
    __shared__ f16x8 lds_F0[SQ];        // 16 KB  F[j][k=0..7]
    __shared__ f16x8 lds_F1[SQ];        // 16 KB  F[j][k=8..15]
    // X^T extended, f16: rows 0..3 = x components, row 4 = ones (denominator).
    __shared__ f16x8 lds_XT[5 * 129];   // ~10.1 KB, pitch 129 f16x8

    const int bid   = blockIdx.x;
    const int b     = bid >> 3;          // 8 row-tiles (of 128) per batch
    const int Ibase = (bid & 7) * ROWS;
    const int tid   = threadIdx.x;

    const float4* xb  = (const float4*)(x + (size_t)b * SQ * 4);
    _Float16*     xtp = (_Float16*)lds_XT;

    // ---- stage: F (f16, swizzled) and X^T+ones (f16); 1 point per thread ----
    {
        int j = tid;
        float4 v = xb[j];
        float c0 = __cosf(0.5f * v.x), s0 = __sinf(0.5f * v.x);
        float c1 = __cosf(0.5f * v.y), s1 = __sinf(0.5f * v.y);
        float c2 = __cosf(0.5f * v.z), s2 = __sinf(0.5f * v.z);
        float c3 = __cosf(0.5f * v.w), s3 = __sinf(0.5f * v.w);
        float m0 = c0 * c1, m1 = s0 * c1, m2 = c0 * s1, m3 = s0 * s1;
        float n0 = m0 * c2, n1 = m1 * c2, n2 = m2 * c2, n3 = m3 * c2;
        float n4 = m0 * s2, n5 = m1 * s2, n6 = m2 * s2, n7 = m3 * s2;
        f16x8 p0, p1;
        p0[0] = (_Float16)(n0 * c3); p0[1] = (_Float16)(n1 * c3);
        p0[2] = (_Float16)(n2 * c3); p0[3] = (_Float16)(n3 * c3);
        p0[4] = (_Float16)(n4 * c3); p0[5] = (_Float16)(n5 * c3);
        p0[6] = (_Float16)(n6 * c3); p0[7] = (_Float16)(n7 * c3);
        p1[0] = (_Float16)(n0 * s3); p1[1] = (_Float16)(n1 * s3);
        p1[2] = (_Float16)(n2 * s3); p1[3] = (_Float16)(n3 * s3);
        p1[4] = (_Float16)(n4 * s3); p1[5] = (_Float16)(n5 * s3);
        p1[6] = (_Float16)(n6 * s3); p1[7] = (_Float16)(n7 * s3);
        int sj = j ^ ((j >> 3) & 7);
        lds_F0[sj] = p0;
        lds_F1[sj] = p1;
        xtp[0 * 1032 + j] = (_Float16)v.x;
        xtp[1 * 1032 + j] = (_Float16)v.y;
        xtp[2 * 1032 + j] = (_Float16)v.z;
        xtp[3 * 1032 + j] = (_Float16)v.w;
        xtp[4 * 1032 + j] = (_Float16)1.0f;
    }
    __syncthreads();

    // ---- main: wave = (row-tile rt, j-quarter q); 8 tiles of 32 j each ----
    const int wid  = tid >> 6;
    const int q    = wid & 3;            // j-quarter: j in [256q, 256q+256)
    const int rt   = wid >> 2;           // row-tile within block (0..3)
    const int lane = tid & 63;
    const int h    = lane >> 5;          // k-half selector
    const int ln   = lane & 31;

    const f16x8* Fh = h ? lds_F1 : lds_F0;
    int ib = Ibase + rt * 32 + ln; ib ^= (ib >> 3) & 7;
    const f16x8 bfrag = Fh[ib];          // B: F[I-tile] rows (col n = i)

    // PV B-frag: lane col n reads X^T row min(n,4); cols >=5 never read back.
    const int rowsel = (ln < 4) ? ln : 4;
    const int xbase  = rowsel * 129 + q * 32 + h;   // f16x8 index

    f32x16 oacc0 = (f32x16)(0.0f);       // e-rows k=j' 0..15
    f32x16 oacc1 = (f32x16)(0.0f);       // e-rows k=j' 16..31

    // Gram for tile 0, pipelined one tile ahead of the poly/PV stage.
    int ja0 = q * 256 + ln;
    f16x8 af0 = Fh[ja0 ^ ((ja0 >> 3) & 7)];
    f32x16 d = __builtin_amdgcn_mfma_f32_32x32x16_f16(
        af0, bfrag, (f32x16)(0.0f), 0, 0, 0);

    #pragma unroll 2
    for (int t = 0; t < 8; ++t) {
        // Issue this iteration's LDS reads first (latency hidden under poly).
        f16x8 afn;
        if (t < 7) {
            int jn = q * 256 + (t + 1) * 32 + ln;
            afn = Fh[jn ^ ((jn >> 3) & 7)];
        }
        f16x8 xf0 = lds_XT[xbase + t * 4];        // X rows [jb, jb+16)
        f16x8 xf1 = lds_XT[xbase + t * 4 + 2];    // X rows [jb+16, jb+32)
        // d[r] = K[j', i], j' = (r&3)+8(r>>2)+4h; e = poly(|d|) in packed f16.
        unsigned q0 = pexp_abs(d[0],  d[1]);
        unsigned q1 = pexp_abs(d[2],  d[3]);
        unsigned q2 = pexp_abs(d[4],  d[5]);
        unsigned q3 = pexp_abs(d[6],  d[7]);
        unsigned q4 = pexp_abs(d[8],  d[9]);
        unsigned q5 = pexp_abs(d[10], d[11]);
        unsigned q6 = pexp_abs(d[12], d[13]);
        unsigned q7 = pexp_abs(d[14], d[15]);
        // Gram for tile t+1; d is dead (consumed above), dn reuses its regs.
        f32x16 dn;
        if (t < 7)
            dn = __builtin_amdgcn_mfma_f32_32x32x16_f16(
                afn, bfrag, (f32x16)(0.0f), 0, 0, 0);
        pl32swap(q0, q2); pl32swap(q1, q3);   // frag0 dwords 0..3 (k = 0..15)
        pl32swap(q4, q6); pl32swap(q5, q7);   // frag1 dwords 0..3 (k = 16..31)
        u32x4 w0 = {q0, q1, q2, q3};
        u32x4 w1 = {q4, q5, q6, q7};
        f16x8 ef0 = __builtin_bit_cast(f16x8, w0);
        f16x8 ef1 = __builtin_bit_cast(f16x8, w1);
        oacc0 = __builtin_amdgcn_mfma_f32_32x32x16_f16(ef0, xf0, oacc0, 0, 0, 0);
        oacc1 = __builtin_amdgcn_mfma_f32_32x32x16_f16(ef1, xf1, oacc1, 0, 0, 0);
        if (t < 7) d = dn;
    }

    // ---- cross-wave combine: partials in LDS (alias onto lds_F0, now dead) ----
    __syncthreads();                     // all waves done reading F / XT
    float* ps = (float*)lds_F0;          // [q=4][128 rows][8 cols f32] = 16 KB
    if (ln < 5) {                        // cols 0..4 valid, both halves
        #pragma unroll
        for (int r = 0; r < 16; ++r) {
            int m = (r & 3) + 8 * (r >> 2) + 4 * h;   // row within 32-tile
            ps[(q * 128 + rt * 32 + m) * 8 + ln] = oacc0[r] + oacc1[r];
        }
    }
    __syncthreads();

    if (tid < ROWS) {
        float nx = 0.f, ny = 0.f, nz = 0.f, nw = 0.f, den = 0.f;
        #pragma unroll
        for (int qq = 0; qq < 4; ++qq) {
            const float* p = &ps[(qq * 128 + tid) * 8];
            nx += p[0]; ny += p[1]; nz += p[2]; nw += p[3]; den += p[4];
        }
        float inv = 1.0f / den;
        ((float4*)out)[(size_t)b * SQ + Ibase + tid] =
            make_float4(nx * inv, ny * inv, nz * inv, nw * inv);
    }
}

extern "C" void kernel_launch(void* const* d_in, const int* in_sizes, int n_in,
                              void* d_out, int out_size, void* d_ws, size_t ws_size,
                              hipStream_t stream) {
    const float* x = (const float*)d_in[0];
    float* out = (float*)d_out;
    dim3 grid(32 * (SQ / ROWS));   // 256 blocks == CU count
    dim3 block(NTHREADS);
    qka_kernel<<<grid, block, 0, stream>>>(x, out);
}